// Round 9
// baseline (215.201 us; speedup 1.0000x reference)
//
#include <hip/hip_runtime.h>

// FocalCTCLoss on MI355X — round 14: heterogeneous grid (MLP-shaped).
// B=256, T=1024, V=128 (BLANK=127), L=64, S=129.
//
// r13 post-mortem: passed, total 200.8->198.5, fused <78.4 (out of top-5)
// but ~65-78 by delta-fit — NOT the predicted 30. Three different consumer
// structures all stall at ~11-12k cy/phase. r10's counters name the wall:
// 1.45 TB/s (18% peak) with barrier-free streamers == per-CU MLP limit.
// One 1024-thread block per CU means each CU pulls its whole 512 KB row
// through ~40 outstanding lines at ~900 cy => ~6 GB/s/CU. The fills hit
// 6.8 TB/s with many small blocks. Fix the occupancy SHAPE, not the
// schedule:
//  - blocks 0..255 (DP, 4 waves): wave0 = r13 consumer (x4 ds_read_b128
//    amortization, CH=32), waves1-2 = transposed label gather, wave3 =
//    blank gather. LDS 16.6 KB -> 8 blocks/CU.
//  - blocks 256..2303 (denom, 2048 blocks = 8 per b): pure streaming
//    row-sum log-denominators, 64 KB/block, no barriers -> fill-like MLP.
//  - numerator/denominator meet in finalize via workspace; zero
//    inter-block sync. Numerics identical to r13 (passed).

#define EPSF 1e-7f

constexpr int Bb  = 256;
constexpr int Tt  = 1024;
constexpr int Vv  = 128;
constexpr int Ll  = 64;
constexpr int CH  = 32;          // timesteps per chunk (DP blocks)
constexpr int NCH = Tt / CH;     // 32 chunks
constexpr int NPH = NCH + 1;     // 33 phases (gather p / consume p-1)
constexpr int NSEG = 8;          // denom segments per batch row

// ---- DPP helpers -----------------------------------------------------------
template <int Ctrl, int RowMask, int BankMask, bool BoundCtrl>
__device__ __forceinline__ float dppf(float x) {
    return __int_as_float(__builtin_amdgcn_update_dpp(
        0, __float_as_int(x), Ctrl, RowMask, BankMask, BoundCtrl));
}

// Half-wave sums: lane 31 = sum(lanes 0..31), lane 63 = sum(lanes 32..63).
__device__ __forceinline__ float half_sum(float x) {
    x += dppf<0x111, 0xf, 0xf, true>(x);
    x += dppf<0x112, 0xf, 0xf, true>(x);
    x += dppf<0x114, 0xf, 0xf, true>(x);
    x += dppf<0x118, 0xf, 0xf, true>(x);
    x += dppf<0x142, 0xa, 0xf, false>(x);
    return x;
}

// Wave-64 max (non-negative inputs), valid on lane 63.
__device__ __forceinline__ float wave_max63(float x) {
    x = fmaxf(x, dppf<0x111, 0xf, 0xf, true>(x));
    x = fmaxf(x, dppf<0x112, 0xf, 0xf, true>(x));
    x = fmaxf(x, dppf<0x114, 0xf, 0xf, true>(x));
    x = fmaxf(x, dppf<0x118, 0xf, 0xf, true>(x));
    x = fmaxf(x, dppf<0x142, 0xa, 0xf, false>(x));
    x = fmaxf(x, dppf<0x143, 0xc, 0xf, false>(x));
    return x;
}

__device__ __forceinline__ float bcast63(float x) {
    return __int_as_float(__builtin_amdgcn_readlane(__float_as_int(x), 63));
}

// ---- DP step (textual; updates a_even/a_odd/a128/eacc in enclosing scope) --
#define DO_STEP(QE, QB, CHK)                                                 \
    do {                                                                     \
        const float am1_ = dppf<0x138, 0xf, 0xf, true>(a_odd);               \
        const float ne_  = (a_even + am1_) * (QB);                           \
        const float no_  = fmaf(maskf, am1_, a_odd + a_even) * (QE);         \
        const float n1_  = (a128 + a_odd) * (QB);                            \
        a_even = ne_; a_odd = no_; a128 = n1_;                               \
        if (CHK) {                                                           \
            const float m_ = fmaxf(fmaxf(a_even, a_odd), a128);              \
            if (__all(m_ < 0x1p-75f)) {                                      \
                const float    wmax_  = bcast63(wave_max63(m_));             \
                const unsigned e_     = __float_as_uint(wmax_) >> 23;        \
                const float    scale_ = __uint_as_float((254u - e_) << 23);  \
                eacc += (int)e_ - 127;                                       \
                a_even *= scale_; a_odd *= scale_; a128 *= scale_;           \
            }                                                                \
        }                                                                    \
    } while (0)

// ---- fused kernel: heterogeneous blocks ------------------------------------
__launch_bounds__(256)
__global__ void fused_kernel(const int* __restrict__ y_true,
                             const float* __restrict__ y_pred,
                             float* __restrict__ num_ws,
                             float* __restrict__ den_ws) {
    const int lane = threadIdx.x & 63;
    const int wv   = threadIdx.x >> 6;  // 0..3

    // DP blocks need the transposed chunk; denom blocks need 32 B.
    __shared__ float4 gt4[2 * (CH / 4) * 64];  // 16 KB
    __shared__ float4 bk4[2 * (CH / 4)];       // 256 B (blank, t-major f4)
    __shared__ float  dpart[8];                // denom half-wave partials

    if (blockIdx.x >= Bb) {
        // ================= denom block: pure streaming ======================
        const int idx = blockIdx.x - Bb;
        const int b   = idx >> 3;          // 0..255
        const int seg = idx & (NSEG - 1);  // 0..7
        const float4* src4 =
            (const float4*)(y_pred + (size_t)b * Tt * Vv) +
            seg * (Tt / NSEG) * (Vv / 4);
        const int h   = 2 * wv + (lane >> 5);  // half-wave 0..7
        const int c32 = lane & 31;
        float ll = 0.0f;
#pragma unroll
        for (int k = 0; k < 16; ++k) {
            const int r = h + 8 * k;  // 0..127 within segment
            const float4 v = src4[r * 32 + c32];
            const float  s = half_sum(v.x + v.y + v.z + v.w);
            if (c32 == 31) ll += __log2f(s + (float)Vv * EPSF);
        }
        if (c32 == 31) dpart[h] = ll;
        __syncthreads();
        if (threadIdx.x == 0) {
            float s = dpart[0] + dpart[1] + dpart[2] + dpart[3] +
                      dpart[4] + dpart[5] + dpart[6] + dpart[7];
            den_ws[seg * Bb + b] = s;
        }
        return;
    }

    // ==================== DP block: gather + serial recursion ===============
    const int    b   = blockIdx.x;
    const float* ygl = y_pred + (size_t)b * Tt * Vv;
    const int    lab = y_true[b * Ll + lane];  // label of odd state 2*lane+1

    // consumer state (wave 0; meaningful on lane 63)
    float a_even = 0.0f, a_odd = 0.0f, a128 = 0.0f, maskf = 0.0f;
    int   eacc = 0;
    if (wv == 0) {
        const int labp = __shfl_up(lab, 1);
        maskf  = (lane == 0 || lab != labp) ? 1.0f : 0.0f;
        a_even = (lane == 0) ? 1.0f : 0.0f;  // pre-t0 init
    }

    for (int p = 0; p < NPH; ++p) {
        if (wv == 3) {
            // blank gather: 32 t's of chunk p, one per lane 0..31
            if (p < NCH && lane < CH) {
                ((float*)(bk4 + (p & 1) * (CH / 4)))[lane] =
                    ygl[(p * CH + lane) * Vv + (Vv - 1)];
            }
        } else if (wv >= 1) {
            // label gather: chunk p -> transposed blocked LDS
            if (p < NCH) {
                const int    tg0 = (wv - 1) * (CH / 2);  // wv1: 0.., wv2: 16..
                const float* src = ygl + p * CH * Vv;
                float* gtw = (float*)(gt4 + (p & 1) * (CH / 4) * 64);
#pragma unroll 8
                for (int j = 0; j < CH / 2; ++j) {
                    const int tl = tg0 + j;
                    gtw[(tl >> 2) * 256 + lane * 4 + (tl & 3)] =
                        src[tl * Vv + lab];
                }
            }
        } else {
            // consumer: 32 DP steps of chunk p-1
            const int c = p - 1;
            if (c >= 0) {
                __builtin_amdgcn_s_setprio(1);
                const float4* gbf = gt4 + (c & 1) * (CH / 4) * 64;
                const float4* bbf = bk4 + (c & 1) * (CH / 4);
                float4 gA = gbf[0 * 64 + lane], gB = gbf[1 * 64 + lane];
                float4 bA = bbf[0],             bB = bbf[1];
#pragma unroll
                for (int i = 0; i < CH / 4; ++i) {
                    DO_STEP(gA.x + EPSF, bA.x + EPSF, false);
                    DO_STEP(gA.y + EPSF, bA.y + EPSF, false);
                    DO_STEP(gA.z + EPSF, bA.z + EPSF, false);
                    DO_STEP(gA.w + EPSF, bA.w + EPSF, (i & 3) == 3);
                    gA = gB; bA = bB;
                    if (i < CH / 4 - 2) {
                        gB = gbf[(i + 2) * 64 + lane];
                        bB = bbf[i + 2];
                    }
                }
                __builtin_amdgcn_s_setprio(0);
            }
        }
        __syncthreads();
    }

    // numerator: log2(alpha_T[last two]) + accumulated exponent
    if (wv == 0 && lane == 63) {
        const float tot = fmaxf(a128 + a_odd, 1e-37f);
        num_ws[b] = __log2f(tot) + (float)eacc;
    }
}

// ---- finalize: combine numerator/denominator, focal transform, mean --------
__global__ void finalize_kernel(const float* __restrict__ num_ws,
                                const float* __restrict__ den_ws,
                                float* __restrict__ out) {
    const int i    = threadIdx.x;  // 256 threads = 4 waves; i == b
    const int lane = i & 63;
    const int wv   = i >> 6;

    float ds = 0.0f;
#pragma unroll
    for (int k = 0; k < NSEG; ++k) ds += den_ws[k * Bb + i];

    const float log2lik = num_ws[i] - ds;
    const float ln_lik  = 0.69314718055994530942f * log2lik;
    const float loss    = -ln_lik;
    const float pp      = __expf(ln_lik);
    const float om      = 1.0f - pp;
    float f = 0.25f * om * om * loss;

#pragma unroll
    for (int off = 32; off > 0; off >>= 1) f += __shfl_xor(f, off);

    __shared__ float red[4];
    if (lane == 0) red[wv] = f;
    __syncthreads();
    if (i == 0)
        out[0] = (red[0] + red[1] + red[2] + red[3]) * (1.0f / (float)Bb);
}

extern "C" void kernel_launch(void* const* d_in, const int* in_sizes, int n_in,
                              void* d_out, int out_size, void* d_ws, size_t ws_size,
                              hipStream_t stream) {
    const int*   y_true = (const int*)d_in[0];    // [B, L] int32
    const float* y_pred = (const float*)d_in[1];  // [B, T, V] float32
    float* num_ws = (float*)d_ws;                 // [B]
    float* den_ws = num_ws + Bb;                  // [NSEG][B]

    fused_kernel<<<Bb + Bb * NSEG, 256, 0, stream>>>(y_true, y_pred,
                                                     num_ws, den_ws);
    finalize_kernel<<<1, 256, 0, stream>>>(num_ws, den_ws, (float*)d_out);
}